// Round 13
// baseline (501.058 us; speedup 1.0000x reference)
//
#include <hip/hip_runtime.h>
#include <hip/hip_bf16.h>

// Problem constants: B=4, S=1024, F=1024, E=8, K=2, H=4*F=4096
constexpr int Ff = 1024;
constexpr int Ee = 8;
constexpr int Hh = 4096;
constexpr int T  = 4096;        // B*S tokens
constexpr int MB = 80;          // 128-row m-units over padded row space (<=10240 rows)

typedef short     bf16x8 __attribute__((ext_vector_type(8)));
typedef float     f32x4  __attribute__((ext_vector_type(4)));
typedef unsigned short u16x8 __attribute__((ext_vector_type(8)));

__device__ __forceinline__ float gelu_fast(float v) {
  // gelu_tanh(v) = v * sigmoid(2*z), z = sqrt(2/pi)*(v + 0.044715 v^3)
  const float c2 = 2.0f * 0.7978845608028654f;
  float z2 = c2 * (v + 0.044715f * v * v * v);
  return v / (1.0f + __expf(-z2));
}

__device__ __forceinline__ unsigned short bf16bits(float f) {
  __hip_bfloat16 h = __float2bfloat16(f);
  return *reinterpret_cast<unsigned short*>(&h);
}

__device__ __forceinline__ void gl_lds16(const void* g, void* l) {
  __builtin_amdgcn_global_load_lds(
      (const __attribute__((address_space(1))) unsigned int*)g,
      (__attribute__((address_space(3))) unsigned int*)l, 16, 0, 0);
}

// ---------------- Gating (fp32, exact routing) ----------------
__global__ __launch_bounds__(256) void gating_kernel(
    const float* __restrict__ x, const float* __restrict__ Wg,
    const float* __restrict__ bg, int* __restrict__ cnt,
    int* __restrict__ list, float* __restrict__ wlist) {
  const int wave = threadIdx.x >> 6;
  const int lane = threadIdx.x & 63;
  const int t = blockIdx.x * 4 + wave;
  float acc[Ee] = {0.f,0.f,0.f,0.f,0.f,0.f,0.f,0.f};
  const float* xrow = x + (size_t)t * Ff;
  for (int f0 = 0; f0 < Ff; f0 += 64) {
    float xv = xrow[f0 + lane];
    const float* wrow = Wg + (size_t)(f0 + lane) * Ee;
    float4 w0 = *reinterpret_cast<const float4*>(wrow);
    float4 w1 = *reinterpret_cast<const float4*>(wrow + 4);
    acc[0] += xv * w0.x; acc[1] += xv * w0.y;
    acc[2] += xv * w0.z; acc[3] += xv * w0.w;
    acc[4] += xv * w1.x; acc[5] += xv * w1.y;
    acc[6] += xv * w1.z; acc[7] += xv * w1.w;
  }
#pragma unroll
  for (int e = 0; e < Ee; ++e) {
#pragma unroll
    for (int off = 32; off; off >>= 1) acc[e] += __shfl_xor(acc[e], off);
  }
  if (lane == 0) {
    float l[Ee], m = -1e30f;
#pragma unroll
    for (int e = 0; e < Ee; ++e) { l[e] = acc[e] + bg[e]; m = fmaxf(m, l[e]); }
    float p[Ee], Z = 0.f;
#pragma unroll
    for (int e = 0; e < Ee; ++e) { p[e] = expf(l[e] - m); Z += p[e]; }
#pragma unroll
    for (int e = 0; e < Ee; ++e) p[e] /= Z;
    int i1 = 0; float p1 = p[0];
#pragma unroll
    for (int e = 1; e < Ee; ++e) if (p[e] > p1) { p1 = p[e]; i1 = e; }
    int i2 = -1; float p2 = -1e30f;
#pragma unroll
    for (int e = 0; e < Ee; ++e) if (e != i1 && p[e] > p2) { p2 = p[e]; i2 = e; }
    float denom = p1 + p2 + 1e-8f;
    int pos = atomicAdd(&cnt[i1], 1);
    list[i1 * T + pos] = t; wlist[i1 * T + pos] = p1 / denom;
    pos = atomicAdd(&cnt[i2], 1);
    list[i2 * T + pos] = t; wlist[i2 * T + pos] = p2 / denom;
  }
}

// 128-aligned expert row offsets (padded flattened row space)
__global__ void prefix_kernel(const int* __restrict__ cnt, int* __restrict__ offs) {
  if (threadIdx.x == 0) {
    int s = 0;
    for (int e = 0; e < Ee; ++e) { offs[e] = s; s += (cnt[e] + 127) & ~127; }
    offs[Ee] = s;
  }
}

// ---- pack_w: src fp32 [K][N] (stride sN) -> dst bf16 units [NB][KT][4][128][8]
__global__ __launch_bounds__(256) void pack_w_kernel(
    const float* __restrict__ src, unsigned short* __restrict__ dst,
    int sN, size_t s_estride, size_t d_estride, int KT) {
  const int e  = blockIdx.z;
  const int nb = blockIdx.x;
  const int kt = blockIdx.y;
  __shared__ float Ts[128][33];
  const int t = threadIdx.x;
  const float* sb = src + (size_t)e * s_estride + (size_t)(kt * 32) * sN + nb * 128;
  {
    const int row = t >> 5;
    const int cc  = (t & 31) * 4;
#pragma unroll
    for (int i = 0; i < 4; ++i) {
      float4 v = *reinterpret_cast<const float4*>(sb + (size_t)(row + 8 * i) * sN + cc);
      Ts[cc + 0][row + 8 * i] = v.x;
      Ts[cc + 1][row + 8 * i] = v.y;
      Ts[cc + 2][row + 8 * i] = v.z;
      Ts[cc + 3][row + 8 * i] = v.w;
    }
  }
  __syncthreads();
  unsigned short* db = dst + (size_t)e * d_estride + ((size_t)nb * KT + kt) * 4096;
#pragma unroll
  for (int j = 0; j < 2; ++j) {
    const int idx = t + 256 * j;
    const int col = idx & 127, kb = idx >> 7;
    u16x8 o;
#pragma unroll
    for (int q = 0; q < 8; ++q) o[q] = bf16bits(Ts[col][kb * 8 + q]);
    *reinterpret_cast<u16x8*>(db + kb * 1024 + col * 8) = o;
  }
}

// ---- pack_x: gather tokens -> xg[mb][kt][4][128][8], zero-filled pads
__global__ __launch_bounds__(256) void pack_x_kernel(
    const float* __restrict__ x, const int* __restrict__ cnt,
    const int* __restrict__ offs, const int* __restrict__ list,
    unsigned short* __restrict__ xg) {
  const int kt = blockIdx.x;
  const int mb = blockIdx.y;
  const int t = threadIdx.x;
  const int m0g = mb * 128;
  int e = 0;
#pragma unroll
  for (int i = 1; i < Ee; ++i) e += (m0g >= offs[i]) ? 1 : 0;
  const int ce = cnt[e];
  const int row = t >> 1, half = t & 1;
  const int mloc = m0g - offs[e] + row;
  const bool valid = (mloc >= 0) && (mloc < ce);
  const int token = valid ? list[e * T + mloc] : 0;
  const float* sp = x + (size_t)token * Ff + kt * 32 + half * 16;
  u16x8 o0, o1;
#pragma unroll
  for (int i = 0; i < 2; ++i) {
    float4 v = valid ? *reinterpret_cast<const float4*>(sp + i * 4)
                     : make_float4(0.f, 0.f, 0.f, 0.f);
    o0[i * 4 + 0] = bf16bits(v.x); o0[i * 4 + 1] = bf16bits(v.y);
    o0[i * 4 + 2] = bf16bits(v.z); o0[i * 4 + 3] = bf16bits(v.w);
  }
#pragma unroll
  for (int i = 2; i < 4; ++i) {
    float4 v = valid ? *reinterpret_cast<const float4*>(sp + i * 4)
                     : make_float4(0.f, 0.f, 0.f, 0.f);
    o1[(i - 2) * 4 + 0] = bf16bits(v.x); o1[(i - 2) * 4 + 1] = bf16bits(v.y);
    o1[(i - 2) * 4 + 2] = bf16bits(v.z); o1[(i - 2) * 4 + 3] = bf16bits(v.w);
  }
  unsigned short* db = xg + ((size_t)mb * (Ff / 32) + kt) * 4096 + row * 8;
  *reinterpret_cast<u16x8*>(db + (half * 2 + 0) * 1024) = o0;
  *reinterpret_cast<u16x8*>(db + (half * 2 + 1) * 1024) = o1;
}

// ======== GEMM1: 128^2, 4 waves, BK=32, depth-3, ONE barrier/iter, 3 blk/CU ========
__global__ __launch_bounds__(256, 3) void gemm1_mfma(
    const unsigned short* __restrict__ xg, const unsigned short* __restrict__ W1P,
    const float* __restrict__ b1, const int* __restrict__ cnt,
    const int* __restrict__ offs, unsigned short* __restrict__ hp, int Hc, int c) {
  const int nxg = Hc >> 7;
  const int nwg = nxg * MB;
  const int raw = blockIdx.x;
  int bid = (raw & 7) * (nwg >> 3) + (raw >> 3);   // XCD gets contiguous range
  const int bw = (nxg >= 4) ? 4 : nxg;             // n-band width
  const int band = bid / (MB * bw);
  const int r2 = bid % (MB * bw);
  const int by = r2 / bw;
  const int bx = band * bw + (r2 % bw);

  const int m0g = by * 128;
  int e = 0;
#pragma unroll
  for (int i = 1; i < Ee; ++i) e += (m0g >= offs[i]) ? 1 : 0;
  const int ce = cnt[e];
  const int mloc = m0g - offs[e];
  if (mloc >= ce) return;
  const int n0 = bx * 128;

  __shared__ __align__(16) unsigned short AsF[3 * 4096];  // 24 KiB
  __shared__ __align__(16) unsigned short BsF[3 * 4096];  // 24 KiB

  const int tid = threadIdx.x;
  const int w = tid >> 6, lane = tid & 63;
  const int g = lane >> 4, r16 = lane & 15;
  const int wr = w >> 1, wc = w & 1;

  constexpr int NT = Ff / 32;    // 32 packed kt-units
  const unsigned short* aU = xg  + (size_t)by * NT * 4096;
  const unsigned short* bU = W1P + (size_t)(e * nxg + bx) * NT * 4096;

  f32x4 acc[4][4] = {};
  auto STAGE = [&](int buf, int kt) {
    const unsigned short* aS = aU + (size_t)kt * 4096 + w * 1024 + lane * 8;
    const unsigned short* bS = bU + (size_t)kt * 4096 + w * 1024 + lane * 8;
    unsigned short* aD = AsF + buf * 4096 + w * 1024;
    unsigned short* bD = BsF + buf * 4096 + w * 1024;
    gl_lds16(aS,       aD);
    gl_lds16(aS + 512, aD + 512);
    gl_lds16(bS,       bD);
    gl_lds16(bS + 512, bD + 512);
  };
  STAGE(0, 0); STAGE(1, 1);
  int cur = 0;
#pragma unroll 1
  for (int t = 0; t < NT; ++t) {
    if (t + 1 < NT) asm volatile("s_waitcnt vmcnt(4)" ::: "memory");
    else            asm volatile("s_waitcnt vmcnt(0)" ::: "memory");
    __builtin_amdgcn_s_barrier();
    asm volatile("" ::: "memory");
    if (t + 2 < NT) STAGE((t + 2) % 3, t + 2);   // buf read at t-1, safe after barrier
    bf16x8 af[4], bfr[4];
#pragma unroll
    for (int i = 0; i < 4; ++i) {
      af[i]  = *reinterpret_cast<const bf16x8*>(
          AsF + cur * 4096 + g * 1024 + (wr * 64 + i * 16 + r16) * 8);
      bfr[i] = *reinterpret_cast<const bf16x8*>(
          BsF + cur * 4096 + g * 1024 + (wc * 64 + i * 16 + r16) * 8);
    }
    asm volatile("s_waitcnt lgkmcnt(0)" ::: "memory");
    __builtin_amdgcn_sched_barrier(0);
    __builtin_amdgcn_s_setprio(1);
#pragma unroll
    for (int mi = 0; mi < 4; ++mi)
#pragma unroll
      for (int ni = 0; ni < 4; ++ni)
        acc[mi][ni] = __builtin_amdgcn_mfma_f32_16x16x32_bf16(
            af[mi], bfr[ni], acc[mi][ni], 0, 0, 0);
    __builtin_amdgcn_s_setprio(0);
    asm volatile("" ::: "memory");
    cur = (cur == 2) ? 0 : cur + 1;
  }
  // epilogue: write hp in packed-A layout (unit = by)
  const int KT2 = Hc >> 5;
  unsigned short* hb = hp + (size_t)by * KT2 * 4096;
#pragma unroll
  for (int ni = 0; ni < 4; ++ni) {
    const int col = n0 + wc * 64 + ni * 16 + r16;
    const float bias = b1[(size_t)e * Hh + (size_t)c * Hc + col];
    unsigned short* hcol = hb + ((size_t)(col >> 5) * 4 + ((col >> 3) & 3)) * 1024 + (col & 7);
#pragma unroll
    for (int mi = 0; mi < 4; ++mi)
#pragma unroll
      for (int r = 0; r < 4; ++r) {
        const int row = wr * 64 + mi * 16 + g * 4 + r;
        if (mloc + row < ce)
          hcol[row * 8] = bf16bits(gelu_fast(acc[mi][ni][r] + bias));
      }
  }
}

// ==== GEMM2: 128^2, 4 waves, BK=32, depth-3, ONE barrier/iter, K-split=2 ====
__global__ __launch_bounds__(256, 3) void gemm2_mfma(
    const unsigned short* __restrict__ hp, const unsigned short* __restrict__ W2P,
    const float* __restrict__ b2, const int* __restrict__ cnt,
    const int* __restrict__ offs, const int* __restrict__ list,
    const float* __restrict__ wlist, float* __restrict__ out,
    int Hc, int kLen, int ksplit, int biasC) {
  constexpr int nxg = Ff >> 7;   // 8
  const int nwg = nxg * MB * ksplit;
  const int raw = blockIdx.x;
  int bid = (raw & 7) * (nwg >> 3) + (raw >> 3);
  const int bx = bid % nxg;      // n fastest -> A-panel reused by co-resident n-blocks
  const int rest = bid / nxg;
  const int by = rest % MB;
  const int bz = rest / MB;

  const int m0g = by * 128;
  int e = 0;
#pragma unroll
  for (int i = 1; i < Ee; ++i) e += (m0g >= offs[i]) ? 1 : 0;
  const int ce = cnt[e];
  const int mloc = m0g - offs[e];
  if (mloc >= ce) return;
  const int n0 = bx * 128;

  __shared__ __align__(16) unsigned short AsF[3 * 4096];
  __shared__ __align__(16) unsigned short BsF[3 * 4096];

  const int tid = threadIdx.x;
  const int w = tid >> 6, lane = tid & 63;
  const int g = lane >> 4, r16 = lane & 15;
  const int wr = w >> 1, wc = w & 1;

  const int KT2 = Hc >> 5;
  const int ktOff = (bz * kLen) >> 5;
  const int NT = kLen >> 5;
  const unsigned short* aU = hp  + ((size_t)by * KT2 + ktOff) * 4096;
  const unsigned short* bU = W2P + ((size_t)(e * nxg + bx) * KT2 + ktOff) * 4096;

  f32x4 acc[4][4] = {};
  auto STAGE = [&](int buf, int kt) {
    const unsigned short* aS = aU + (size_t)kt * 4096 + w * 1024 + lane * 8;
    const unsigned short* bS = bU + (size_t)kt * 4096 + w * 1024 + lane * 8;
    unsigned short* aD = AsF + buf * 4096 + w * 1024;
    unsigned short* bD = BsF + buf * 4096 + w * 1024;
    gl_lds16(aS,       aD);
    gl_lds16(aS + 512, aD + 512);
    gl_lds16(bS,       bD);
    gl_lds16(bS + 512, bD + 512);
  };
  STAGE(0, 0);
  if (NT > 1) STAGE(1, 1);
  int cur = 0;
#pragma unroll 1
  for (int t = 0; t < NT; ++t) {
    if (t + 1 < NT) asm volatile("s_waitcnt vmcnt(4)" ::: "memory");
    else            asm volatile("s_waitcnt vmcnt(0)" ::: "memory");
    __builtin_amdgcn_s_barrier();
    asm volatile("" ::: "memory");
    if (t + 2 < NT) STAGE((t + 2) % 3, t + 2);
    bf16x8 af[4], bfr[4];
#pragma unroll
    for (int i = 0; i < 4; ++i) {
      af[i]  = *reinterpret_cast<const bf16x8*>(
          AsF + cur * 4096 + g * 1024 + (wr * 64 + i * 16 + r16) * 8);
      bfr[i] = *reinterpret_cast<const bf16x8*>(
          BsF + cur * 4096 + g * 1024 + (wc * 64 + i * 16 + r16) * 8);
    }
    asm volatile("s_waitcnt lgkmcnt(0)" ::: "memory");
    __builtin_amdgcn_sched_barrier(0);
    __builtin_amdgcn_s_setprio(1);
#pragma unroll
    for (int mi = 0; mi < 4; ++mi)
#pragma unroll
      for (int ni = 0; ni < 4; ++ni)
        acc[mi][ni] = __builtin_amdgcn_mfma_f32_16x16x32_bf16(
            af[mi], bfr[ni], acc[mi][ni], 0, 0, 0);
    __builtin_amdgcn_s_setprio(0);
    asm volatile("" ::: "memory");
    cur = (cur == 2) ? 0 : cur + 1;
  }
  const bool addBias = (biasC != 0) && (bz == 0);
#pragma unroll
  for (int mi = 0; mi < 4; ++mi)
#pragma unroll
    for (int r = 0; r < 4; ++r) {
      const int row = wr * 64 + mi * 16 + g * 4 + r;
      if (mloc + row >= ce) continue;
      const int token = list[e * T + mloc + row];
      const float wgt = wlist[e * T + mloc + row];
      float* op = out + (size_t)token * Ff;
#pragma unroll
      for (int ni = 0; ni < 4; ++ni) {
        const int col = n0 + wc * 64 + ni * 16 + r16;
        float v = acc[mi][ni][r];
        if (addBias) v += b2[(size_t)e * Ff + col];
        atomicAdd(&op[col], wgt * v);
      }
    }
}

extern "C" void kernel_launch(void* const* d_in, const int* in_sizes, int n_in,
                              void* d_out, int out_size, void* d_ws, size_t ws_size,
                              hipStream_t stream) {
  const float* x  = (const float*)d_in[0];
  const float* Wg = (const float*)d_in[1];
  const float* bg = (const float*)d_in[2];
  const float* W1 = (const float*)d_in[3];
  const float* b1 = (const float*)d_in[4];
  const float* W2 = (const float*)d_in[5];
  const float* b2 = (const float*)d_in[6];
  float* out = (float*)d_out;

  // fixed = ctrl + lists + xg(80 units x 1024 k, bf16); per-Hc-unit = W1P + W2P + hp
  const size_t fixed = 1024 + 2 * (size_t)T * Ee * 4 + (size_t)MB * 128 * Ff * 2;
  int Hc = 4096;
  while (Hc > 256 && fixed + (size_t)Hc * 53248 > ws_size) Hc >>= 1;
  const int nchunk = Hh / Hc;
  const int ksplit = 2;
  const int kLen = Hc / ksplit;   // >= 128

  char* p = (char*)d_ws;
  int*   cnt   = (int*)p;            p += 512;
  int*   offs  = (int*)p;            p += 512;
  int*   list  = (int*)p;            p += (size_t)T * Ee * 4;
  float* wlist = (float*)p;          p += (size_t)T * Ee * 4;
  unsigned short* xg  = (unsigned short*)p;  p += (size_t)MB * 128 * Ff * 2;
  unsigned short* W1P = (unsigned short*)p;  p += (size_t)Ee * Hc * Ff * 2;
  unsigned short* W2P = (unsigned short*)p;  p += (size_t)Ee * Ff * Hc * 2;
  unsigned short* hp  = (unsigned short*)p;  // MB*128 x Hc x 2

  hipMemsetAsync(d_out, 0, (size_t)out_size * sizeof(float), stream);
  hipMemsetAsync(cnt, 0, 64, stream);

  gating_kernel<<<T / 4, 256, 0, stream>>>(x, Wg, bg, cnt, list, wlist);
  prefix_kernel<<<1, 64, 0, stream>>>(cnt, offs);
  pack_x_kernel<<<dim3(Ff / 32, MB), 256, 0, stream>>>(x, cnt, offs, list, xg);

  for (int c = 0; c < nchunk; ++c) {
    pack_w_kernel<<<dim3(Hc / 128, Ff / 32, Ee), 256, 0, stream>>>(
        W1 + (size_t)c * Hc, W1P, Hh, (size_t)Ff * Hh, (size_t)Hc * Ff, Ff / 32);
    pack_w_kernel<<<dim3(Ff / 128, Hc / 32, Ee), 256, 0, stream>>>(
        W2 + (size_t)c * Hc * Ff, W2P, Ff, (size_t)Hh * Ff, (size_t)Ff * Hc, Hc / 32);
    gemm1_mfma<<<(Hc / 128) * MB, 256, 0, stream>>>(
        xg, W1P, b1, cnt, offs, hp, Hc, c);
    gemm2_mfma<<<(Ff / 128) * MB * ksplit, 256, 0, stream>>>(
        hp, W2P, b2, cnt, offs, list, wlist, out, Hc, kLen, ksplit,
        c == nchunk - 1 ? 1 : 0);
  }
}

// Round 14
// 432.539 us; speedup vs baseline: 1.1584x; 1.1584x over previous
//
#include <hip/hip_runtime.h>
#include <hip/hip_bf16.h>

// Problem constants: B=4, S=1024, F=1024, E=8, K=2, H=4*F=4096
constexpr int Ff = 1024;
constexpr int Ee = 8;
constexpr int Hh = 4096;
constexpr int T  = 4096;        // B*S tokens
constexpr int MB = 80;          // 128-row m-units over padded row space (<=10240 rows)

typedef short     bf16x8 __attribute__((ext_vector_type(8)));
typedef float     f32x4  __attribute__((ext_vector_type(4)));
typedef unsigned short u16x8 __attribute__((ext_vector_type(8)));

__device__ __forceinline__ float gelu_fast(float v) {
  // gelu_tanh(v) = v * sigmoid(2*z), z = sqrt(2/pi)*(v + 0.044715 v^3)
  const float c2 = 2.0f * 0.7978845608028654f;
  float z2 = c2 * (v + 0.044715f * v * v * v);
  return v / (1.0f + __expf(-z2));
}

__device__ __forceinline__ unsigned short bf16bits(float f) {
  __hip_bfloat16 h = __float2bfloat16(f);
  return *reinterpret_cast<unsigned short*>(&h);
}

__device__ __forceinline__ void gl_lds16(const void* g, void* l) {
  __builtin_amdgcn_global_load_lds(
      (const __attribute__((address_space(1))) unsigned int*)g,
      (__attribute__((address_space(3))) unsigned int*)l, 16, 0, 0);
}

// ---------------- Gating (fp32, exact routing) ----------------
__global__ __launch_bounds__(256) void gating_kernel(
    const float* __restrict__ x, const float* __restrict__ Wg,
    const float* __restrict__ bg, int* __restrict__ cnt,
    int* __restrict__ list, float* __restrict__ wlist) {
  const int wave = threadIdx.x >> 6;
  const int lane = threadIdx.x & 63;
  const int t = blockIdx.x * 4 + wave;
  float acc[Ee] = {0.f,0.f,0.f,0.f,0.f,0.f,0.f,0.f};
  const float* xrow = x + (size_t)t * Ff;
  for (int f0 = 0; f0 < Ff; f0 += 64) {
    float xv = xrow[f0 + lane];
    const float* wrow = Wg + (size_t)(f0 + lane) * Ee;
    float4 w0 = *reinterpret_cast<const float4*>(wrow);
    float4 w1 = *reinterpret_cast<const float4*>(wrow + 4);
    acc[0] += xv * w0.x; acc[1] += xv * w0.y;
    acc[2] += xv * w0.z; acc[3] += xv * w0.w;
    acc[4] += xv * w1.x; acc[5] += xv * w1.y;
    acc[6] += xv * w1.z; acc[7] += xv * w1.w;
  }
#pragma unroll
  for (int e = 0; e < Ee; ++e) {
#pragma unroll
    for (int off = 32; off; off >>= 1) acc[e] += __shfl_xor(acc[e], off);
  }
  if (lane == 0) {
    float l[Ee], m = -1e30f;
#pragma unroll
    for (int e = 0; e < Ee; ++e) { l[e] = acc[e] + bg[e]; m = fmaxf(m, l[e]); }
    float p[Ee], Z = 0.f;
#pragma unroll
    for (int e = 0; e < Ee; ++e) { p[e] = expf(l[e] - m); Z += p[e]; }
#pragma unroll
    for (int e = 0; e < Ee; ++e) p[e] /= Z;
    int i1 = 0; float p1 = p[0];
#pragma unroll
    for (int e = 1; e < Ee; ++e) if (p[e] > p1) { p1 = p[e]; i1 = e; }
    int i2 = -1; float p2 = -1e30f;
#pragma unroll
    for (int e = 0; e < Ee; ++e) if (e != i1 && p[e] > p2) { p2 = p[e]; i2 = e; }
    float denom = p1 + p2 + 1e-8f;
    int pos = atomicAdd(&cnt[i1], 1);
    list[i1 * T + pos] = t; wlist[i1 * T + pos] = p1 / denom;
    pos = atomicAdd(&cnt[i2], 1);
    list[i2 * T + pos] = t; wlist[i2 * T + pos] = p2 / denom;
  }
}

// 128-aligned expert row offsets (padded flattened row space)
__global__ void prefix_kernel(const int* __restrict__ cnt, int* __restrict__ offs) {
  if (threadIdx.x == 0) {
    int s = 0;
    for (int e = 0; e < Ee; ++e) { offs[e] = s; s += (cnt[e] + 127) & ~127; }
    offs[Ee] = s;
  }
}

// ---- pack_w: src fp32 [K][N] (stride sN) -> dst bf16 units [NB][KT][4][128][8]
__global__ __launch_bounds__(256) void pack_w_kernel(
    const float* __restrict__ src, unsigned short* __restrict__ dst,
    int sN, size_t s_estride, size_t d_estride, int KT) {
  const int e  = blockIdx.z;
  const int nb = blockIdx.x;
  const int kt = blockIdx.y;
  __shared__ float Ts[128][33];
  const int t = threadIdx.x;
  const float* sb = src + (size_t)e * s_estride + (size_t)(kt * 32) * sN + nb * 128;
  {
    const int row = t >> 5;
    const int cc  = (t & 31) * 4;
#pragma unroll
    for (int i = 0; i < 4; ++i) {
      float4 v = *reinterpret_cast<const float4*>(sb + (size_t)(row + 8 * i) * sN + cc);
      Ts[cc + 0][row + 8 * i] = v.x;
      Ts[cc + 1][row + 8 * i] = v.y;
      Ts[cc + 2][row + 8 * i] = v.z;
      Ts[cc + 3][row + 8 * i] = v.w;
    }
  }
  __syncthreads();
  unsigned short* db = dst + (size_t)e * d_estride + ((size_t)nb * KT + kt) * 4096;
#pragma unroll
  for (int j = 0; j < 2; ++j) {
    const int idx = t + 256 * j;
    const int col = idx & 127, kb = idx >> 7;
    u16x8 o;
#pragma unroll
    for (int q = 0; q < 8; ++q) o[q] = bf16bits(Ts[col][kb * 8 + q]);
    *reinterpret_cast<u16x8*>(db + kb * 1024 + col * 8) = o;
  }
}

// ---- pack_x: gather tokens -> xg[mb][kt][4][128][8], zero-filled pads
__global__ __launch_bounds__(256) void pack_x_kernel(
    const float* __restrict__ x, const int* __restrict__ cnt,
    const int* __restrict__ offs, const int* __restrict__ list,
    unsigned short* __restrict__ xg) {
  const int kt = blockIdx.x;
  const int mb = blockIdx.y;
  const int t = threadIdx.x;
  const int m0g = mb * 128;
  int e = 0;
#pragma unroll
  for (int i = 1; i < Ee; ++i) e += (m0g >= offs[i]) ? 1 : 0;
  const int ce = cnt[e];
  const int row = t >> 1, half = t & 1;
  const int mloc = m0g - offs[e] + row;
  const bool valid = (mloc >= 0) && (mloc < ce);
  const int token = valid ? list[e * T + mloc] : 0;
  const float* sp = x + (size_t)token * Ff + kt * 32 + half * 16;
  u16x8 o0, o1;
#pragma unroll
  for (int i = 0; i < 2; ++i) {
    float4 v = valid ? *reinterpret_cast<const float4*>(sp + i * 4)
                     : make_float4(0.f, 0.f, 0.f, 0.f);
    o0[i * 4 + 0] = bf16bits(v.x); o0[i * 4 + 1] = bf16bits(v.y);
    o0[i * 4 + 2] = bf16bits(v.z); o0[i * 4 + 3] = bf16bits(v.w);
  }
#pragma unroll
  for (int i = 2; i < 4; ++i) {
    float4 v = valid ? *reinterpret_cast<const float4*>(sp + i * 4)
                     : make_float4(0.f, 0.f, 0.f, 0.f);
    o1[(i - 2) * 4 + 0] = bf16bits(v.x); o1[(i - 2) * 4 + 1] = bf16bits(v.y);
    o1[(i - 2) * 4 + 2] = bf16bits(v.z); o1[(i - 2) * 4 + 3] = bf16bits(v.w);
  }
  unsigned short* db = xg + ((size_t)mb * (Ff / 32) + kt) * 4096 + row * 8;
  *reinterpret_cast<u16x8*>(db + (half * 2 + 0) * 1024) = o0;
  *reinterpret_cast<u16x8*>(db + (half * 2 + 1) * 1024) = o1;
}

// ======== GEMM1: 128^2, 4 waves, BK=32, depth-3 (r12 schedule), LDS-coalesced epilogue ========
__global__ __launch_bounds__(256, 3) void gemm1_mfma(
    const unsigned short* __restrict__ xg, const unsigned short* __restrict__ W1P,
    const float* __restrict__ b1, const int* __restrict__ cnt,
    const int* __restrict__ offs, unsigned short* __restrict__ hp, int Hc, int c) {
  const int nxg = Hc >> 7;
  const int nwg = nxg * MB;
  const int raw = blockIdx.x;
  int bid = (raw & 7) * (nwg >> 3) + (raw >> 3);   // XCD gets contiguous range
  const int bw = (nxg >= 4) ? 4 : nxg;             // n-band width
  const int band = bid / (MB * bw);
  const int r2 = bid % (MB * bw);
  const int by = r2 / bw;
  const int bx = band * bw + (r2 % bw);

  const int m0g = by * 128;
  int e = 0;
#pragma unroll
  for (int i = 1; i < Ee; ++i) e += (m0g >= offs[i]) ? 1 : 0;
  const int ce = cnt[e];
  const int mloc = m0g - offs[e];
  if (mloc >= ce) return;
  const int n0 = bx * 128;

  __shared__ __align__(16) unsigned short SMEM[24576];  // 48 KiB (stage bufs / out tile)
  unsigned short* AsF = SMEM;           // 3 x 4096
  unsigned short* BsF = SMEM + 12288;   // 3 x 4096

  const int tid = threadIdx.x;
  const int w = tid >> 6, lane = tid & 63;
  const int g = lane >> 4, r16 = lane & 15;
  const int wr = w >> 1, wc = w & 1;

  constexpr int NT = Ff / 32;    // 32 packed kt-units
  const unsigned short* aU = xg  + (size_t)by * NT * 4096;
  const unsigned short* bU = W1P + (size_t)(e * nxg + bx) * NT * 4096;

  f32x4 acc[4][4] = {};
  auto STAGE = [&](int buf, int kt) {
    const unsigned short* aS = aU + (size_t)kt * 4096 + w * 1024 + lane * 8;
    const unsigned short* bS = bU + (size_t)kt * 4096 + w * 1024 + lane * 8;
    unsigned short* aD = AsF + buf * 4096 + w * 1024;
    unsigned short* bD = BsF + buf * 4096 + w * 1024;
    gl_lds16(aS,       aD);
    gl_lds16(aS + 512, aD + 512);
    gl_lds16(bS,       bD);
    gl_lds16(bS + 512, bD + 512);
  };
  STAGE(0, 0); STAGE(1, 1); STAGE(2, 2);
  int cur = 0;
#pragma unroll 1
  for (int t = 0; t < NT; ++t) {
    const int rem = NT - t;
    if (rem >= 3)      asm volatile("s_waitcnt vmcnt(8)" ::: "memory");
    else if (rem == 2) asm volatile("s_waitcnt vmcnt(4)" ::: "memory");
    else               asm volatile("s_waitcnt vmcnt(0)" ::: "memory");
    __builtin_amdgcn_s_barrier();
    asm volatile("" ::: "memory");
    bf16x8 af[4], bfr[4];
#pragma unroll
    for (int i = 0; i < 4; ++i) {
      af[i]  = *reinterpret_cast<const bf16x8*>(
          AsF + cur * 4096 + g * 1024 + (wr * 64 + i * 16 + r16) * 8);
      bfr[i] = *reinterpret_cast<const bf16x8*>(
          BsF + cur * 4096 + g * 1024 + (wc * 64 + i * 16 + r16) * 8);
    }
    asm volatile("s_waitcnt lgkmcnt(0)" ::: "memory");
    __builtin_amdgcn_sched_barrier(0);
    __builtin_amdgcn_s_barrier();
    if (t + 3 < NT) STAGE(cur, t + 3);   // (t+3)%3 == cur
    __builtin_amdgcn_s_setprio(1);
#pragma unroll
    for (int mi = 0; mi < 4; ++mi)
#pragma unroll
      for (int ni = 0; ni < 4; ++ni)
        acc[mi][ni] = __builtin_amdgcn_mfma_f32_16x16x32_bf16(
            af[mi], bfr[ni], acc[mi][ni], 0, 0, 0);
    __builtin_amdgcn_s_setprio(0);
    asm volatile("" ::: "memory");
    cur = (cur == 2) ? 0 : cur + 1;
  }
  // ---- epilogue: bf16 tile through LDS, then coalesced packed-hp stores ----
  __builtin_amdgcn_s_barrier();          // all waves done reading stage bufs
  unsigned short (*Ls)[136] = reinterpret_cast<unsigned short(*)[136]>(SMEM);
#pragma unroll
  for (int ni = 0; ni < 4; ++ni) {
    const int col = wc * 64 + ni * 16 + r16;
    const float bias = b1[(size_t)e * Hh + (size_t)c * Hc + n0 + col];
#pragma unroll
    for (int mi = 0; mi < 4; ++mi)
#pragma unroll
      for (int r = 0; r < 4; ++r) {
        const int row = wr * 64 + mi * 16 + g * 4 + r;
        Ls[row][col] = bf16bits(gelu_fast(acc[mi][ni][r] + bias));
      }
  }
  __builtin_amdgcn_s_barrier();
  // packed-hp layout: unit=by, per 32-col group: [kt2][kb][row][8]
  unsigned short* hb2 = hp + (size_t)by * (Hc >> 5) * 4096 + (size_t)(n0 >> 5) * 4096;
#pragma unroll
  for (int p = 0; p < 8; ++p) {
    const int u = p * 256 + tid;        // 0..2047
    const int oct = u >> 7;             // 0..15 : col octet
    const int row = u & 127;            // lanes vary over row -> contiguous 16B stores
    const int lc = oct * 8;
    unsigned short* dst = hb2 + ((size_t)((lc >> 5) * 4 + ((lc >> 3) & 3))) * 1024 + row * 8;
    *reinterpret_cast<u16x8*>(dst) = *reinterpret_cast<const u16x8*>(&Ls[row][lc]);
  }
}

// ==== GEMM2: 128^2, 4 waves, BK=32, depth-3 (r12 schedule), K-split=2 ====
__global__ __launch_bounds__(256, 3) void gemm2_mfma(
    const unsigned short* __restrict__ hp, const unsigned short* __restrict__ W2P,
    const float* __restrict__ b2, const int* __restrict__ cnt,
    const int* __restrict__ offs, const int* __restrict__ list,
    const float* __restrict__ wlist, float* __restrict__ out,
    int Hc, int kLen, int ksplit, int biasC) {
  constexpr int nxg = Ff >> 7;   // 8
  const int nwg = nxg * MB * ksplit;
  const int raw = blockIdx.x;
  int bid = (raw & 7) * (nwg >> 3) + (raw >> 3);
  const int bx = bid % nxg;      // n fastest -> A-panel reused by co-resident n-blocks
  const int rest = bid / nxg;
  const int by = rest % MB;
  const int bz = rest / MB;

  const int m0g = by * 128;
  int e = 0;
#pragma unroll
  for (int i = 1; i < Ee; ++i) e += (m0g >= offs[i]) ? 1 : 0;
  const int ce = cnt[e];
  const int mloc = m0g - offs[e];
  if (mloc >= ce) return;
  const int n0 = bx * 128;

  __shared__ __align__(16) unsigned short AsF[3 * 4096];
  __shared__ __align__(16) unsigned short BsF[3 * 4096];

  const int tid = threadIdx.x;
  const int w = tid >> 6, lane = tid & 63;
  const int g = lane >> 4, r16 = lane & 15;
  const int wr = w >> 1, wc = w & 1;

  const int KT2 = Hc >> 5;
  const int ktOff = (bz * kLen) >> 5;
  const int NT = kLen >> 5;
  const unsigned short* aU = hp  + ((size_t)by * KT2 + ktOff) * 4096;
  const unsigned short* bU = W2P + ((size_t)(e * nxg + bx) * KT2 + ktOff) * 4096;

  f32x4 acc[4][4] = {};
  auto STAGE = [&](int buf, int kt) {
    const unsigned short* aS = aU + (size_t)kt * 4096 + w * 1024 + lane * 8;
    const unsigned short* bS = bU + (size_t)kt * 4096 + w * 1024 + lane * 8;
    unsigned short* aD = AsF + buf * 4096 + w * 1024;
    unsigned short* bD = BsF + buf * 4096 + w * 1024;
    gl_lds16(aS,       aD);
    gl_lds16(aS + 512, aD + 512);
    gl_lds16(bS,       bD);
    gl_lds16(bS + 512, bD + 512);
  };
  STAGE(0, 0);
  if (NT > 1) STAGE(1, 1);
  if (NT > 2) STAGE(2, 2);
  int cur = 0;
#pragma unroll 1
  for (int t = 0; t < NT; ++t) {
    const int rem = NT - t;
    if (rem >= 3)      asm volatile("s_waitcnt vmcnt(8)" ::: "memory");
    else if (rem == 2) asm volatile("s_waitcnt vmcnt(4)" ::: "memory");
    else               asm volatile("s_waitcnt vmcnt(0)" ::: "memory");
    __builtin_amdgcn_s_barrier();
    asm volatile("" ::: "memory");
    bf16x8 af[4], bfr[4];
#pragma unroll
    for (int i = 0; i < 4; ++i) {
      af[i]  = *reinterpret_cast<const bf16x8*>(
          AsF + cur * 4096 + g * 1024 + (wr * 64 + i * 16 + r16) * 8);
      bfr[i] = *reinterpret_cast<const bf16x8*>(
          BsF + cur * 4096 + g * 1024 + (wc * 64 + i * 16 + r16) * 8);
    }
    asm volatile("s_waitcnt lgkmcnt(0)" ::: "memory");
    __builtin_amdgcn_sched_barrier(0);
    __builtin_amdgcn_s_barrier();
    if (t + 3 < NT) STAGE(cur, t + 3);
    __builtin_amdgcn_s_setprio(1);
#pragma unroll
    for (int mi = 0; mi < 4; ++mi)
#pragma unroll
      for (int ni = 0; ni < 4; ++ni)
        acc[mi][ni] = __builtin_amdgcn_mfma_f32_16x16x32_bf16(
            af[mi], bfr[ni], acc[mi][ni], 0, 0, 0);
    __builtin_amdgcn_s_setprio(0);
    asm volatile("" ::: "memory");
    cur = (cur == 2) ? 0 : cur + 1;
  }
  const bool addBias = (biasC != 0) && (bz == 0);
#pragma unroll
  for (int mi = 0; mi < 4; ++mi)
#pragma unroll
    for (int r = 0; r < 4; ++r) {
      const int row = wr * 64 + mi * 16 + g * 4 + r;
      if (mloc + row >= ce) continue;
      const int token = list[e * T + mloc + row];
      const float wgt = wlist[e * T + mloc + row];
      float* op = out + (size_t)token * Ff;
#pragma unroll
      for (int ni = 0; ni < 4; ++ni) {
        const int col = n0 + wc * 64 + ni * 16 + r16;
        float v = acc[mi][ni][r];
        if (addBias) v += b2[(size_t)e * Ff + col];
        atomicAdd(&op[col], wgt * v);
      }
    }
}

extern "C" void kernel_launch(void* const* d_in, const int* in_sizes, int n_in,
                              void* d_out, int out_size, void* d_ws, size_t ws_size,
                              hipStream_t stream) {
  const float* x  = (const float*)d_in[0];
  const float* Wg = (const float*)d_in[1];
  const float* bg = (const float*)d_in[2];
  const float* W1 = (const float*)d_in[3];
  const float* b1 = (const float*)d_in[4];
  const float* W2 = (const float*)d_in[5];
  const float* b2 = (const float*)d_in[6];
  float* out = (float*)d_out;

  // fixed = ctrl + lists + xg(80 units x 1024 k, bf16); per-Hc-unit = W1P + W2P + hp
  const size_t fixed = 1024 + 2 * (size_t)T * Ee * 4 + (size_t)MB * 128 * Ff * 2;
  int Hc = 4096;
  while (Hc > 256 && fixed + (size_t)Hc * 53248 > ws_size) Hc >>= 1;
  const int nchunk = Hh / Hc;
  const int ksplit = 2;
  const int kLen = Hc / ksplit;   // >= 128

  char* p = (char*)d_ws;
  int*   cnt   = (int*)p;            p += 512;
  int*   offs  = (int*)p;            p += 512;
  int*   list  = (int*)p;            p += (size_t)T * Ee * 4;
  float* wlist = (float*)p;          p += (size_t)T * Ee * 4;
  unsigned short* xg  = (unsigned short*)p;  p += (size_t)MB * 128 * Ff * 2;
  unsigned short* W1P = (unsigned short*)p;  p += (size_t)Ee * Hc * Ff * 2;
  unsigned short* W2P = (unsigned short*)p;  p += (size_t)Ee * Ff * Hc * 2;
  unsigned short* hp  = (unsigned short*)p;  // MB*128 x Hc x 2

  hipMemsetAsync(d_out, 0, (size_t)out_size * sizeof(float), stream);
  hipMemsetAsync(cnt, 0, 64, stream);

  gating_kernel<<<T / 4, 256, 0, stream>>>(x, Wg, bg, cnt, list, wlist);
  prefix_kernel<<<1, 64, 0, stream>>>(cnt, offs);
  pack_x_kernel<<<dim3(Ff / 32, MB), 256, 0, stream>>>(x, cnt, offs, list, xg);

  for (int c = 0; c < nchunk; ++c) {
    pack_w_kernel<<<dim3(Hc / 128, Ff / 32, Ee), 256, 0, stream>>>(
        W1 + (size_t)c * Hc, W1P, Hh, (size_t)Ff * Hh, (size_t)Hc * Ff, Ff / 32);
    pack_w_kernel<<<dim3(Ff / 128, Hc / 32, Ee), 256, 0, stream>>>(
        W2 + (size_t)c * Hc * Ff, W2P, Ff, (size_t)Hh * Ff, (size_t)Ff * Hc, Hc / 32);
    gemm1_mfma<<<(Hc / 128) * MB, 256, 0, stream>>>(
        xg, W1P, b1, cnt, offs, hp, Hc, c);
    gemm2_mfma<<<(Ff / 128) * MB * ksplit, 256, 0, stream>>>(
        hp, W2P, b2, cnt, offs, list, wlist, out, Hc, kLen, ksplit,
        c == nchunk - 1 ? 1 : 0);
  }
}